// Round 5
// baseline (130.350 us; speedup 1.0000x reference)
//
#include <hip/hip_runtime.h>

typedef __bf16 bf16x8 __attribute__((ext_vector_type(8)));
typedef float f32x4 __attribute__((ext_vector_type(4)));
typedef unsigned int u32x4 __attribute__((ext_vector_type(4)));

__device__ __forceinline__ unsigned short f2bf(float f) {
  unsigned u = __builtin_bit_cast(unsigned, f);
  u += 0x7FFFu + ((u >> 16) & 1u);
  return (unsigned short)(u >> 16);
}

// async global->LDS, 16B per lane. LDS dest = wave-uniform base + lane*16 (HW rule).
__device__ __forceinline__ void gl2lds16(const void* g, void* l) {
  __builtin_amdgcn_global_load_lds((const __attribute__((address_space(1))) void*)g,
                                   (__attribute__((address_space(3))) void*)l, 16, 0, 0);
}

__device__ __forceinline__ bf16x8 cvt8v(f32x4 a, f32x4 b) {
  bf16x8 r;
  r[0] = (__bf16)a[0]; r[1] = (__bf16)a[1]; r[2] = (__bf16)a[2]; r[3] = (__bf16)a[3];
  r[4] = (__bf16)b[0]; r[5] = (__bf16)b[1]; r[6] = (__bf16)b[2]; r[7] = (__bf16)b[3];
  return r;
}

// ---------------- W transpose: W[512 f][512 d] f32 -> Wt[512 d][512 f] bf16 --------
__global__ void transpose_cvt(const float* __restrict__ in, unsigned short* __restrict__ out) {
  __shared__ float tile[32][33];
  const int r0 = blockIdx.x * 32, c0 = blockIdx.y * 32;
  const int tx = threadIdx.x, ty = threadIdx.y;
#pragma unroll
  for (int i = 0; i < 4; ++i) tile[ty + i * 8][tx] = in[(size_t)(r0 + ty + i * 8) * 512 + c0 + tx];
  __syncthreads();
#pragma unroll
  for (int i = 0; i < 4; ++i) {
    const int cc = ty + i * 8;
    out[(size_t)(c0 + cc) * 512 + r0 + tx] = f2bf(tile[tx][cc]);
  }
}

// ---------------- frag-ordered m97-style GEMM --------------------------------------
// 128x128 block tile, BK=64, 256 threads = 4 waves in 2x2 (wr,wc); wave tile 64x64.
// LDS holds FRAGMENTS in lane order: each 1KB region = one wave-fragment, lane L's
// 16B at fragbase + L*16 (global_load_lds linear dest; per-lane SOURCE address is
// permuted to deliver exactly the element frag-lane L needs). ds_read_b128 is then
// stride-1 by lane -> zero bank conflicts, single shared vaddr + imm offsets.
// A-frags fp32 (cvt to bf16 on read): [wr2][mi4][kk2][h2] = 32KB.
// B-frags bf16: [wc2][ni4][kk2] = 16KB. Total 48KB -> 2 blocks/CU at grid 512;
// cross-block overlap hides the syncthreads vmcnt-drain (m97/m114 mechanism).
template <int APITCH, int BPITCH, int NT, bool IS_Y>
__global__ __launch_bounds__(256, 2) void gemm_frag(const float* __restrict__ A0,
                                                    const unsigned short* __restrict__ B0,
                                                    unsigned short* __restrict__ yT,
                                                    int* __restrict__ mask,
                                                    float* __restrict__ out) {
  __shared__ __align__(16) char lds[49152];
  char* ldsA = lds;            // 32 x 1KB A-frags
  char* ldsB = lds + 32768;    // 16 x 1KB B-frags

  const int bid = blockIdx.x;
  int b, m0loc, n0;
  const float* Ab;
  const unsigned short* Bb;
  if constexpr (IS_Y) {
    const int mt = bid >> 2, nt = bid & 3;     // 128 M-tiles x 4 N-tiles
    b = mt >> 4;
    m0loc = (mt & 15) * 128;
    n0 = nt * 128;
    Ab = A0 + ((size_t)b * 2048 + m0loc) * APITCH;   // x[b][m0..][.]
    Bb = B0 + (size_t)n0 * BPITCH;                   // wT[n0..][.]
  } else {
    b = bid & 7;                                // batch -> XCD pin (yT[b] locality)
    const int idx = bid >> 3;
    m0loc = (idx & 15) * 128;
    n0 = (idx >> 4) * 128;
    Ab = A0 + ((size_t)b * 2048 + m0loc) * APITCH;   // a[b][m0..][.]
    Bb = B0 + ((size_t)b * 512 + n0) * BPITCH;       // yT[b][n0..][.]
  }

  const int tid = threadIdx.x, w = tid >> 6, lane = tid & 63;
  const int wr = w >> 1, wc = w & 1, r = lane & 15, hi = lane >> 4;
  const int lof = lane * 16;

  // per-lane source base: row += lane&15, k += (lane>>4)*8 (elements)
  const float* apv = Ab + (size_t)(lane & 15) * APITCH + (lane >> 4) * 8;
  const unsigned short* bpv = Bb + (size_t)(lane & 15) * BPITCH + (lane >> 4) * 8;

  f32x4 acc[4][4] = {};
  unsigned anz[4] = {0u, 0u, 0u, 0u};

#pragma unroll 1
  for (int t = 0; t < NT; ++t) {
    const int k0 = t * 64;
    // stage A: 8 glds/wave; frag id g = (wr<<4)|(mi<<2)|(kk<<1)|h
#pragma unroll
    for (int j = 0; j < 8; ++j) {
      const int g = w * 8 + j;
      const int gwr = g >> 4, gmi = (g >> 2) & 3, gkk = (g >> 1) & 1, gh = g & 1;
      gl2lds16(apv + k0 + (size_t)(gwr * 64 + gmi * 16) * APITCH + gkk * 32 + gh * 4,
               ldsA + g * 1024);
    }
    // stage B: 4 glds/wave; frag id g2 = (wc<<3)|(ni<<1)|kk
#pragma unroll
    for (int j = 0; j < 4; ++j) {
      const int g2 = w * 4 + j;
      const int gwc = g2 >> 3, gni = (g2 >> 1) & 3, gkk = g2 & 1;
      gl2lds16(bpv + k0 + (size_t)(gwc * 64 + gni * 16) * BPITCH + gkk * 32,
               ldsB + g2 * 1024);
    }
    __syncthreads();  // compiler-inserted vmcnt(0): tile resident

    bf16x8 bf[4][2];
#pragma unroll
    for (int ni = 0; ni < 4; ++ni)
#pragma unroll
      for (int kk = 0; kk < 2; ++kk)
        bf[ni][kk] = *(const bf16x8*)(ldsB + (((wc << 3) | (ni << 1) | kk) << 10) + lof);

#pragma unroll
    for (int kk = 0; kk < 2; ++kk)
#pragma unroll
      for (int mi = 0; mi < 4; ++mi) {
        f32x4 lo = *(const f32x4*)(ldsA + (((wr << 4) | (mi << 2) | (kk << 1)) << 10) + lof);
        f32x4 hh = *(const f32x4*)(ldsA + ((((wr << 4) | (mi << 2) | (kk << 1)) | 1) << 10) + lof);
        if constexpr (IS_Y) {
          if (wc == 0) {  // exact row mask from raw fp32 bits (pre-cvt)
            u32x4 u0 = __builtin_bit_cast(u32x4, lo), u1 = __builtin_bit_cast(u32x4, hh);
            anz[mi] |= (u0[0] | u0[1] | u0[2] | u0[3] | u1[0] | u1[1] | u1[2] | u1[3]) &
                       0x7fffffffu;
          }
        }
        bf16x8 af = cvt8v(lo, hh);
#pragma unroll
        for (int ni = 0; ni < 4; ++ni)
          acc[mi][ni] =
              __builtin_amdgcn_mfma_f32_16x16x32_bf16(af, bf[ni][kk], acc[mi][ni], 0, 0, 0);
      }
    if (t + 1 < NT) __syncthreads();  // all reads done before next overwrite
  }

  if constexpr (IS_Y) {
    if (wc == 0) {
#pragma unroll
      for (int mi = 0; mi < 4; ++mi) {
        unsigned v = anz[mi];
        v |= __shfl_xor(v, 16);
        v |= __shfl_xor(v, 32);
        if (hi == 0) mask[b * 2048 + m0loc + wr * 64 + mi * 16 + r] = (v != 0u) ? 1 : 0;
      }
    }
    // yT[b][d][n]: rr runs along n -> contiguous 8B stores
#pragma unroll
    for (int mi = 0; mi < 4; ++mi)
#pragma unroll
      for (int ni = 0; ni < 4; ++ni) {
        const int col = n0 + wc * 64 + ni * 16 + r;
        const int nrow = m0loc + wr * 64 + mi * 16 + hi * 4;
        ushort4 s;
        s.x = f2bf(acc[mi][ni][0]);
        s.y = f2bf(acc[mi][ni][1]);
        s.z = f2bf(acc[mi][ni][2]);
        s.w = f2bf(acc[mi][ni][3]);
        *(ushort4*)(yT + (((size_t)b * 512 + col) << 11) + nrow) = s;
      }
  } else {
    const int* mrow = mask + b * 2048 + m0loc + wr * 64;
#pragma unroll
    for (int mi = 0; mi < 4; ++mi) {
      const int4 mv = *(const int4*)(mrow + mi * 16 + hi * 4);
      const int mvv[4] = {mv.x, mv.y, mv.z, mv.w};
#pragma unroll
      for (int ni = 0; ni < 4; ++ni) {
        const int col = n0 + wc * 64 + ni * 16 + r;
        float* op = out + (size_t)(b * 2048 + m0loc + wr * 64 + mi * 16 + hi * 4) * 512 + col;
#pragma unroll
        for (int rr = 0; rr < 4; ++rr) {
          float v = fmaxf(acc[mi][ni][rr], 0.0f);
          if (mvv[rr] == 0) v = 0.0f;
          op[(size_t)rr * 512] = v;
        }
      }
    }
  }
}

// ---------------- launch ----------------------------------------------------------
extern "C" void kernel_launch(void* const* d_in, const int* in_sizes, int n_in,
                              void* d_out, int out_size, void* d_ws, size_t ws_size,
                              hipStream_t stream) {
  const float* x = (const float*)d_in[0];   // [8][2048][512]
  const float* a = (const float*)d_in[1];   // [8][2048][2048]
  const float* wk = (const float*)d_in[2];  // [512][512]
  float* out = (float*)d_out;               // [8][2048][512]

  char* ws = (char*)d_ws;
  unsigned short* wT = (unsigned short*)ws;                 // 512 KB
  unsigned short* yT = (unsigned short*)(ws + (1u << 19));  // 16 MB
  int* mask = (int*)(ws + (1u << 19) + (16u << 20));        // 64 KB

  transpose_cvt<<<dim3(16, 16), dim3(32, 8), 0, stream>>>(wk, wT);
  // y^T = (x @ W)^T (bf16) + exact row mask.  M=16384, N=512, K=512.
  gemm_frag<512, 512, 8, true><<<512, 256, 0, stream>>>(x, wT, yT, mask, nullptr);
  // out = relu(a @ y) * mask.  Per batch M=2048, N=512, K=2048.
  gemm_frag<2048, 2048, 32, false><<<512, 256, 0, stream>>>(a, yT, nullptr, mask, out);
}

// Round 6
// 128.040 us; speedup vs baseline: 1.0180x; 1.0180x over previous
//
#include <hip/hip_runtime.h>

typedef __bf16 bf16x8 __attribute__((ext_vector_type(8)));
typedef float f32x4 __attribute__((ext_vector_type(4)));
typedef unsigned int u32x4 __attribute__((ext_vector_type(4)));

__device__ __forceinline__ unsigned short f2bf(float f) {
  unsigned u = __builtin_bit_cast(unsigned, f);
  u += 0x7FFFu + ((u >> 16) & 1u);
  return (unsigned short)(u >> 16);
}

// opaque (un-sinkable) 16B global load with literal byte offset
template <int OFF>
__device__ __forceinline__ u32x4 gld16(const void* p) {
  u32x4 r;
  asm volatile("global_load_dwordx4 %0, %1, off offset:%2" : "=v"(r) : "v"(p), "n"(OFF));
  return r;
}

__device__ __forceinline__ bf16x8 cvt8v(f32x4 a, f32x4 b) {
  bf16x8 r;
  r[0] = (__bf16)a[0]; r[1] = (__bf16)a[1]; r[2] = (__bf16)a[2]; r[3] = (__bf16)a[3];
  r[4] = (__bf16)b[0]; r[5] = (__bf16)b[1]; r[6] = (__bf16)b[2]; r[7] = (__bf16)b[3];
  return r;
}

// ---------------- W transpose: W[512 f][512 d] f32 -> Wt[512 d][512 f] bf16 --------
__global__ void transpose_cvt(const float* __restrict__ in, unsigned short* __restrict__ out) {
  __shared__ float tile[32][33];
  const int r0 = blockIdx.x * 32, c0 = blockIdx.y * 32;
  const int tx = threadIdx.x, ty = threadIdx.y;
#pragma unroll
  for (int i = 0; i < 4; ++i) tile[ty + i * 8][tx] = in[(size_t)(r0 + ty + i * 8) * 512 + c0 + tx];
  __syncthreads();
#pragma unroll
  for (int i = 0; i < 4; ++i) {
    const int cc = ty + i * 8;
    out[(size_t)(c0 + cc) * 512 + r0 + tx] = f2bf(tile[tx][cc]);
  }
}

// ---------------- T14 one-barrier double-buffered frag-ordered GEMM ---------------
// 128x128 tile, BK=64, 256 thr = 4 waves (2x2). LDS: bf16 frag-ordered, dbuf:
// [buf][A 16KB | B 16KB] = 64KB -> 2 blocks/CU. Per K-step:
//   issue 12 asm loads(t+1) -> ds_read+MFMA(t) -> vmcnt(0) -> cvt+ds_write(t+1)
//   -> ONE __syncthreads (nothing in flight at barrier => drain is free).
// A fp32 cvt'd in registers; frag-ordered LDS => stride-1 lane reads, 0 conflicts.
template <int APITCH, int BPITCH, int NT, bool IS_Y>
__global__ __launch_bounds__(256, 2) void gemm_t14(const float* __restrict__ A0,
                                                   const unsigned short* __restrict__ B0,
                                                   unsigned short* __restrict__ yT,
                                                   int* __restrict__ mask,
                                                   float* __restrict__ out) {
  __shared__ __align__(16) char lds[65536];

  const int bid = blockIdx.x;
  int b, m0loc, n0;
  const float* Ab;
  const unsigned short* Bb;
  if constexpr (IS_Y) {
    const int mt = bid >> 2, nt = bid & 3;  // 128 m-tiles x 4 n-tiles
    b = mt >> 4;
    m0loc = (mt & 15) * 128;
    n0 = nt * 128;
    Ab = A0 + ((size_t)b * 2048 + m0loc) * APITCH;
    Bb = B0 + (size_t)n0 * BPITCH;
  } else {
    b = bid & 7;  // batch -> XCD pin (yT[b] L2 locality)
    const int idx = bid >> 3;
    m0loc = (idx & 15) * 128;
    n0 = (idx >> 4) * 128;
    Ab = A0 + ((size_t)b * 2048 + m0loc) * APITCH;
    Bb = B0 + ((size_t)b * 512 + n0) * BPITCH;
  }

  const int tid = threadIdx.x, w = tid >> 6, L = tid & 63;
  const int wr = w >> 1, wc = w & 1, r = L & 15, hi = L >> 4;
  const int Lof = L * 16;

  // staging sources: rows (w*32 + jj*16 + r), k = kk*32 + hi*8 (+4)
  const char* aPtr0 = (const char*)(Ab + (size_t)(w * 32 + r) * APITCH + hi * 8);
  const char* aPtr1 = (const char*)(Ab + (size_t)(w * 32 + 16 + r) * APITCH + hi * 8);
  const char* bPtr0 = (const char*)(Bb + (size_t)(w * 32 + r) * BPITCH + hi * 8);
  const char* bPtr1 = (const char*)(Bb + (size_t)(w * 32 + 16 + r) * BPITCH + hi * 8);

  // LDS write offsets: frag g = w*4 + jj*2 + kk (A), +16KB for B
  int aWof[2][2], bWof[2][2];
#pragma unroll
  for (int jj = 0; jj < 2; ++jj)
#pragma unroll
    for (int kk = 0; kk < 2; ++kk) {
      aWof[jj][kk] = ((w * 4 + jj * 2 + kk) << 10) + Lof;
      bWof[jj][kk] = 16384 + ((w * 4 + jj * 2 + kk) << 10) + Lof;
    }

  f32x4 acc[4][4] = {};
  unsigned anz[2] = {0u, 0u};
  u32x4 la000, la001, la010, la011, la100, la101, la110, la111;  // A (jj,kk,h)
  u32x4 lb00, lb01, lb10, lb11;                                  // B (jj,kk)

#define LOADS(T1)                                                     \
  {                                                                   \
    const int ao = (T1) * 256, bo = (T1) * 128;                       \
    la000 = gld16<0>(aPtr0 + ao);   la001 = gld16<16>(aPtr0 + ao);    \
    la010 = gld16<128>(aPtr0 + ao); la011 = gld16<144>(aPtr0 + ao);   \
    la100 = gld16<0>(aPtr1 + ao);   la101 = gld16<16>(aPtr1 + ao);    \
    la110 = gld16<128>(aPtr1 + ao); la111 = gld16<144>(aPtr1 + ao);   \
    lb00 = gld16<0>(bPtr0 + bo);    lb01 = gld16<64>(bPtr0 + bo);     \
    lb10 = gld16<0>(bPtr1 + bo);    lb11 = gld16<64>(bPtr1 + bo);     \
    __builtin_amdgcn_sched_barrier(0);                                \
  }

#define WR_A(BASE, jj, kk, x0, x1)                                          \
  {                                                                         \
    f32x4 lo = __builtin_bit_cast(f32x4, x0);                               \
    f32x4 hh = __builtin_bit_cast(f32x4, x1);                               \
    if constexpr (IS_Y) {                                                   \
      anz[jj] |= ((x0)[0] | (x0)[1] | (x0)[2] | (x0)[3] | (x1)[0] |         \
                  (x1)[1] | (x1)[2] | (x1)[3]) & 0x7fffffffu;               \
    }                                                                       \
    *(bf16x8*)((BASE) + aWof[jj][kk]) = cvt8v(lo, hh);                      \
  }

#define STAGE_WRITE(BUF)                                                    \
  {                                                                         \
    char* base = lds + (BUF) * 32768;                                       \
    asm volatile("s_waitcnt vmcnt(0)" ::: "memory");                        \
    __builtin_amdgcn_sched_barrier(0);                                      \
    WR_A(base, 0, 0, la000, la001)                                          \
    WR_A(base, 0, 1, la010, la011)                                          \
    WR_A(base, 1, 0, la100, la101)                                          \
    WR_A(base, 1, 1, la110, la111)                                          \
    *(bf16x8*)(base + bWof[0][0]) = __builtin_bit_cast(bf16x8, lb00);       \
    *(bf16x8*)(base + bWof[0][1]) = __builtin_bit_cast(bf16x8, lb01);       \
    *(bf16x8*)(base + bWof[1][0]) = __builtin_bit_cast(bf16x8, lb10);       \
    *(bf16x8*)(base + bWof[1][1]) = __builtin_bit_cast(bf16x8, lb11);       \
  }

#define COMPUTE(BUF)                                                        \
  {                                                                         \
    const char* base = lds + (BUF) * 32768;                                 \
    bf16x8 bfr[4][2];                                                       \
    _Pragma("unroll") for (int ni = 0; ni < 4; ++ni)                        \
        _Pragma("unroll") for (int kk = 0; kk < 2; ++kk)                    \
            bfr[ni][kk] = *(const bf16x8*)(base + 16384 +                   \
                (((wc << 3) | (ni << 1) | kk) << 10) + Lof);                \
    _Pragma("unroll") for (int kk = 0; kk < 2; ++kk)                        \
        _Pragma("unroll") for (int mi = 0; mi < 4; ++mi) {                  \
          bf16x8 af = *(const bf16x8*)(base +                               \
              (((wr << 3) | (mi << 1) | kk) << 10) + Lof);                  \
          _Pragma("unroll") for (int ni = 0; ni < 4; ++ni)                  \
              acc[mi][ni] = __builtin_amdgcn_mfma_f32_16x16x32_bf16(        \
                  af, bfr[ni][kk], acc[mi][ni], 0, 0, 0);                   \
        }                                                                   \
  }

  // prologue: stage tile 0 into buf0
  LOADS(0)
  STAGE_WRITE(0)
  __syncthreads();

#pragma unroll 1
  for (int t = 0; t < NT - 2; t += 2) {
    LOADS(t + 1) COMPUTE(0) STAGE_WRITE(1) __syncthreads();
    LOADS(t + 2) COMPUTE(1) STAGE_WRITE(0) __syncthreads();
  }
  LOADS(NT - 1) COMPUTE(0) STAGE_WRITE(1) __syncthreads();
  COMPUTE(1)

#undef LOADS
#undef WR_A
#undef STAGE_WRITE
#undef COMPUTE

  if constexpr (IS_Y) {
    // exact row mask from pre-cvt fp32 bits; rows w*32 + jj*16 + r, k-reduce over hi
#pragma unroll
    for (int jj = 0; jj < 2; ++jj) {
      unsigned v = anz[jj];
      v |= __shfl_xor(v, 16);
      v |= __shfl_xor(v, 32);
      if (hi == 0) mask[b * 2048 + m0loc + w * 32 + jj * 16 + r] = (v != 0u) ? 1 : 0;
    }
    // yT[b][d][n]: rr runs along n -> contiguous 8B stores
#pragma unroll
    for (int mi = 0; mi < 4; ++mi)
#pragma unroll
      for (int ni = 0; ni < 4; ++ni) {
        const int col = n0 + wc * 64 + ni * 16 + r;
        const int nrow = m0loc + wr * 64 + mi * 16 + hi * 4;
        ushort4 s;
        s.x = f2bf(acc[mi][ni][0]);
        s.y = f2bf(acc[mi][ni][1]);
        s.z = f2bf(acc[mi][ni][2]);
        s.w = f2bf(acc[mi][ni][3]);
        *(ushort4*)(yT + (((size_t)b * 512 + col) << 11) + nrow) = s;
      }
  } else {
    const int* mrow = mask + b * 2048 + m0loc + wr * 64;
#pragma unroll
    for (int mi = 0; mi < 4; ++mi) {
      const int4 mv = *(const int4*)(mrow + mi * 16 + hi * 4);
      const int mvv[4] = {mv.x, mv.y, mv.z, mv.w};
#pragma unroll
      for (int ni = 0; ni < 4; ++ni) {
        const int col = n0 + wc * 64 + ni * 16 + r;
        float* op = out + (size_t)(b * 2048 + m0loc + wr * 64 + mi * 16 + hi * 4) * 512 + col;
#pragma unroll
        for (int rr = 0; rr < 4; ++rr) {
          float v = fmaxf(acc[mi][ni][rr], 0.0f);
          if (mvv[rr] == 0) v = 0.0f;
          op[(size_t)rr * 512] = v;
        }
      }
    }
  }
}

// ---------------- launch ----------------------------------------------------------
extern "C" void kernel_launch(void* const* d_in, const int* in_sizes, int n_in,
                              void* d_out, int out_size, void* d_ws, size_t ws_size,
                              hipStream_t stream) {
  const float* x = (const float*)d_in[0];   // [8][2048][512]
  const float* a = (const float*)d_in[1];   // [8][2048][2048]
  const float* wk = (const float*)d_in[2];  // [512][512]
  float* out = (float*)d_out;               // [8][2048][512]

  char* ws = (char*)d_ws;
  unsigned short* wT = (unsigned short*)ws;                 // 512 KB
  unsigned short* yT = (unsigned short*)(ws + (1u << 19));  // 16 MB
  int* mask = (int*)(ws + (1u << 19) + (16u << 20));        // 64 KB

  transpose_cvt<<<dim3(16, 16), dim3(32, 8), 0, stream>>>(wk, wT);
  // y^T = (x @ W)^T (bf16) + exact row mask.  M=16384, N=512, K=512.
  gemm_t14<512, 512, 8, true><<<512, 256, 0, stream>>>(x, wT, yT, mask, nullptr);
  // out = relu(a @ y) * mask.  Per batch M=2048, N=512, K=2048.
  gemm_t14<2048, 2048, 32, false><<<512, 256, 0, stream>>>(a, yT, nullptr, mask, out);
}

// Round 7
// 112.275 us; speedup vs baseline: 1.1610x; 1.1404x over previous
//
#include <hip/hip_runtime.h>

typedef __bf16 bf16x8 __attribute__((ext_vector_type(8)));
typedef float f32x4 __attribute__((ext_vector_type(4)));
typedef unsigned int u32x4 __attribute__((ext_vector_type(4)));

__device__ __forceinline__ unsigned short f2bf(float f) {
  unsigned u = __builtin_bit_cast(unsigned, f);
  u += 0x7FFFu + ((u >> 16) & 1u);
  return (unsigned short)(u >> 16);
}

// opaque (un-sinkable) 16B global load with literal byte offset
template <int OFF>
__device__ __forceinline__ u32x4 gld16(const char* p) {
  u32x4 r;
  asm volatile("global_load_dwordx4 %0, %1, off offset:%2" : "=v"(r) : "v"(p), "n"(OFF));
  return r;
}

__device__ __forceinline__ f32x4 asf(u32x4 u) { return __builtin_bit_cast(f32x4, u); }

__device__ __forceinline__ bf16x8 cvt8v(f32x4 a, f32x4 b) {
  bf16x8 r;
  r[0] = (__bf16)a[0]; r[1] = (__bf16)a[1]; r[2] = (__bf16)a[2]; r[3] = (__bf16)a[3];
  r[4] = (__bf16)b[0]; r[5] = (__bf16)b[1]; r[6] = (__bf16)b[2]; r[7] = (__bf16)b[3];
  return r;
}

// ---------------- W transpose: W[512 f][512 d] f32 -> Wt[512 d][512 f] bf16 --------
__global__ void transpose_cvt(const float* __restrict__ in, unsigned short* __restrict__ out) {
  __shared__ float tile[32][33];
  const int r0 = blockIdx.x * 32, c0 = blockIdx.y * 32;
  const int tx = threadIdx.x, ty = threadIdx.y;
#pragma unroll
  for (int i = 0; i < 4; ++i) tile[ty + i * 8][tx] = in[(size_t)(r0 + ty + i * 8) * 512 + c0 + tx];
  __syncthreads();
#pragma unroll
  for (int i = 0; i < 4; ++i) {
    const int cc = ty + i * 8;
    out[(size_t)(c0 + cc) * 512 + r0 + tx] = f2bf(tile[tx][cc]);
  }
}

// ---------------- traffic-cut T14 GEMM: 128(M) x 256(N) tile, BK=64 ---------------
// 512 thr = 8 waves (2 wr x 4 wc), wave tile 64x64 (acc 4x4 f32x4).
// Single 48KB frag-ordered bf16 LDS buffer (A 16KB: frag fA=mi*2+kk; B 32KB:
// fB=outer*2+kk, outer=wc*4+ni). Per iter: 8 asm loads(t+1) held in regs ->
// ds_read+32 MFMA(t) -> lgkm+s_barrier (loads STAY in flight) -> vmcnt(0) ->
// cvt+ds_write(t+1) -> lgkm+s_barrier. Traffic: A read (512/256)=2x, B read
// (16384/128)=128 blocks x 1MB -> 396 MB total vs round-6's 768 MB.
template <int APITCH, int BPITCH, int NT, bool IS_Y>
__global__ __launch_bounds__(512, 2) void gemm_tc(const float* __restrict__ A0,
                                                  const unsigned short* __restrict__ B0,
                                                  unsigned short* __restrict__ yT,
                                                  int* __restrict__ mask,
                                                  float* __restrict__ out) {
  __shared__ __align__(16) char lds[49152];

  const int bid = blockIdx.x;
  int b, m0b, n0;
  const float* Ab;
  const unsigned short* Bb;
  if constexpr (IS_Y) {
    const int mt = bid >> 1, nt = bid & 1;  // 128 m-tiles x 2 n-tiles
    b = mt >> 4;
    m0b = (mt & 15) * 128;
    n0 = nt * 256;
    Ab = A0 + ((size_t)b * 2048 + m0b) * APITCH;
    Bb = B0 + (size_t)n0 * BPITCH;
  } else {
    b = bid & 7;  // batch -> XCD pin (yT[b] L2 locality)
    const int idx = bid >> 3;
    m0b = (idx & 15) * 128;
    n0 = (idx >> 4) * 256;
    Ab = A0 + ((size_t)b * 2048 + m0b) * APITCH;
    Bb = B0 + ((size_t)b * 512 + n0) * BPITCH;
  }

  const int tid = threadIdx.x, w = tid >> 6, L = tid & 63;
  const int wr = w >> 2, wc = w & 3, r = L & 15, hi = L >> 4;
  const int Lof = L * 16;

  // staging sources. A: wave w stages rows w*16+(L&15), kk=j (frag fA = w*2+j).
  // B: wave w stages outer 2w,2w+1 -> rows w*32+{0,16}+(L&15) (frag fB = w*4+j).
  const char* aP0 = (const char*)(Ab + (size_t)(w * 16 + r) * APITCH + hi * 8);
  const char* aP1 = aP0 + 128;  // kk=1 -> +32 fp32
  const char* bP0 = (const char*)(Bb + (size_t)(w * 32 + r) * BPITCH + hi * 8);
  const char* bP1 = bP0 + 64;   // kk=1 -> +32 bf16
  const char* bP2 = (const char*)(Bb + (size_t)(w * 32 + 16 + r) * BPITCH + hi * 8);
  const char* bP3 = bP2 + 64;

  f32x4 acc[4][4] = {};
  unsigned anz = 0u;
  u32x4 la00, la01, la10, la11, lb0, lb1, lb2, lb3;

#define LOADS()                                                   \
  {                                                               \
    la00 = gld16<0>(aP0); la01 = gld16<16>(aP0);                  \
    la10 = gld16<0>(aP1); la11 = gld16<16>(aP1);                  \
    lb0 = gld16<0>(bP0);  lb1 = gld16<0>(bP1);                    \
    lb2 = gld16<0>(bP2);  lb3 = gld16<0>(bP3);                    \
    __builtin_amdgcn_sched_barrier(0);                            \
    aP0 += 256; aP1 += 256;                                       \
    bP0 += 128; bP1 += 128; bP2 += 128; bP3 += 128;               \
  }

#define WRITE()                                                                \
  {                                                                            \
    if constexpr (IS_Y) {                                                      \
      anz |= (la00[0] | la00[1] | la00[2] | la00[3] | la01[0] | la01[1] |      \
              la01[2] | la01[3] | la10[0] | la10[1] | la10[2] | la10[3] |      \
              la11[0] | la11[1] | la11[2] | la11[3]) & 0x7fffffffu;            \
    }                                                                          \
    *(bf16x8*)(lds + ((w * 2 + 0) << 10) + Lof) = cvt8v(asf(la00), asf(la01)); \
    *(bf16x8*)(lds + ((w * 2 + 1) << 10) + Lof) = cvt8v(asf(la10), asf(la11)); \
    *(bf16x8*)(lds + 16384 + ((w * 4 + 0) << 10) + Lof) = __builtin_bit_cast(bf16x8, lb0); \
    *(bf16x8*)(lds + 16384 + ((w * 4 + 1) << 10) + Lof) = __builtin_bit_cast(bf16x8, lb1); \
    *(bf16x8*)(lds + 16384 + ((w * 4 + 2) << 10) + Lof) = __builtin_bit_cast(bf16x8, lb2); \
    *(bf16x8*)(lds + 16384 + ((w * 4 + 3) << 10) + Lof) = __builtin_bit_cast(bf16x8, lb3); \
  }

#define COMPUTE()                                                              \
  {                                                                            \
    bf16x8 bfr[4][2];                                                          \
    _Pragma("unroll") for (int ni = 0; ni < 4; ++ni)                           \
        _Pragma("unroll") for (int kk = 0; kk < 2; ++kk)                       \
            bfr[ni][kk] = *(const bf16x8*)(lds + 16384 +                       \
                (((wc * 4 + ni) * 2 + kk) << 10) + Lof);                       \
    _Pragma("unroll") for (int kk = 0; kk < 2; ++kk)                           \
        _Pragma("unroll") for (int mi = 0; mi < 4; ++mi) {                     \
          bf16x8 af = *(const bf16x8*)(lds +                                   \
              (((wr * 4 + mi) * 2 + kk) << 10) + Lof);                         \
          _Pragma("unroll") for (int ni = 0; ni < 4; ++ni)                     \
              acc[mi][ni] = __builtin_amdgcn_mfma_f32_16x16x32_bf16(           \
                  af, bfr[ni][kk], acc[mi][ni], 0, 0, 0);                      \
        }                                                                      \
  }

#define BAR_LG()                                                  \
  {                                                               \
    asm volatile("s_waitcnt lgkmcnt(0)" ::: "memory");            \
    __builtin_amdgcn_sched_barrier(0);                            \
    __builtin_amdgcn_s_barrier();                                 \
    __builtin_amdgcn_sched_barrier(0);                            \
  }

#define WAIT_VM()                                                 \
  {                                                               \
    asm volatile("s_waitcnt vmcnt(0)" ::: "memory");              \
    __builtin_amdgcn_sched_barrier(0);                            \
  }

  // prologue: stage tile 0
  LOADS()
  WAIT_VM()
  WRITE()
  BAR_LG()

#pragma unroll 1
  for (int t = 0; t < NT - 1; ++t) {
    LOADS()        // tile t+1 -> regs (in flight through COMPUTE and barrier 1)
    COMPUTE()      // tile t from LDS
    BAR_LG()       // readers done; globals still in flight
    WAIT_VM()      // loads landed (mostly covered by MFMA above)
    WRITE()        // tile t+1 -> LDS
    BAR_LG()       // writers done
  }
  COMPUTE()        // tile NT-1

#undef LOADS
#undef WRITE
#undef COMPUTE
#undef BAR_LG
#undef WAIT_VM

  if constexpr (IS_Y) {
    // exact row mask: wave w staged rows m0b + w*16 + (L&15); reduce over hi groups
    unsigned v = anz;
    v |= __shfl_xor(v, 16);
    v |= __shfl_xor(v, 32);
    if (hi == 0) mask[b * 2048 + m0b + w * 16 + r] = (v != 0u) ? 1 : 0;
    // yT[b][d][n] store: rr runs along n -> contiguous 8B stores
#pragma unroll
    for (int mi = 0; mi < 4; ++mi)
#pragma unroll
      for (int ni = 0; ni < 4; ++ni) {
        const int col = n0 + wc * 64 + ni * 16 + r;
        const int nrow = m0b + wr * 64 + mi * 16 + hi * 4;
        ushort4 s;
        s.x = f2bf(acc[mi][ni][0]);
        s.y = f2bf(acc[mi][ni][1]);
        s.z = f2bf(acc[mi][ni][2]);
        s.w = f2bf(acc[mi][ni][3]);
        *(ushort4*)(yT + (((size_t)b * 512 + col) << 11) + nrow) = s;
      }
  } else {
    const int* mrow = mask + b * 2048 + m0b + wr * 64;
#pragma unroll
    for (int mi = 0; mi < 4; ++mi) {
      const int4 mv = *(const int4*)(mrow + mi * 16 + hi * 4);
      const int mvv[4] = {mv.x, mv.y, mv.z, mv.w};
#pragma unroll
      for (int ni = 0; ni < 4; ++ni) {
        const int col = n0 + wc * 64 + ni * 16 + r;
        float* op = out + (size_t)(b * 2048 + m0b + wr * 64 + mi * 16 + hi * 4) * 512 + col;
#pragma unroll
        for (int rr = 0; rr < 4; ++rr) {
          float v = fmaxf(acc[mi][ni][rr], 0.0f);
          if (mvv[rr] == 0) v = 0.0f;
          op[(size_t)rr * 512] = v;
        }
      }
    }
  }
}

// ---------------- launch ----------------------------------------------------------
extern "C" void kernel_launch(void* const* d_in, const int* in_sizes, int n_in,
                              void* d_out, int out_size, void* d_ws, size_t ws_size,
                              hipStream_t stream) {
  const float* x = (const float*)d_in[0];   // [8][2048][512]
  const float* a = (const float*)d_in[1];   // [8][2048][2048]
  const float* wk = (const float*)d_in[2];  // [512][512]
  float* out = (float*)d_out;               // [8][2048][512]

  char* ws = (char*)d_ws;
  unsigned short* wT = (unsigned short*)ws;                 // 512 KB
  unsigned short* yT = (unsigned short*)(ws + (1u << 19));  // 16 MB
  int* mask = (int*)(ws + (1u << 19) + (16u << 20));        // 64 KB

  transpose_cvt<<<dim3(16, 16), dim3(32, 8), 0, stream>>>(wk, wT);
  // y^T = (x @ W)^T (bf16) + exact row mask.  M=16384 flat, N=512, K=512.
  gemm_tc<512, 512, 8, true><<<256, 512, 0, stream>>>(x, wT, yT, mask, nullptr);
  // out = relu(a @ y) * mask.  Per batch M=2048, N=512, K=2048.
  gemm_tc<2048, 2048, 32, false><<<256, 512, 0, stream>>>(a, yT, nullptr, mask, out);
}

// Round 8
// 99.495 us; speedup vs baseline: 1.3101x; 1.1284x over previous
//
#include <hip/hip_runtime.h>

typedef __bf16 bf16x8 __attribute__((ext_vector_type(8)));
typedef float f32x4 __attribute__((ext_vector_type(4)));
typedef unsigned int u32x4 __attribute__((ext_vector_type(4)));

__device__ __forceinline__ unsigned short f2bf(float f) {
  unsigned u = __builtin_bit_cast(unsigned, f);
  u += 0x7FFFu + ((u >> 16) & 1u);
  return (unsigned short)(u >> 16);
}

// async global->LDS, 16B/lane; LDS dest = wave-uniform base + lane*16 (HW rule)
__device__ __forceinline__ void gl2lds16(const void* g, void* l) {
  __builtin_amdgcn_global_load_lds((const __attribute__((address_space(1))) void*)g,
                                   (__attribute__((address_space(3))) void*)l, 16, 0, 0);
}

__device__ __forceinline__ bf16x8 cvt8v(f32x4 a, f32x4 b) {
  bf16x8 r;
  r[0] = (__bf16)a[0]; r[1] = (__bf16)a[1]; r[2] = (__bf16)a[2]; r[3] = (__bf16)a[3];
  r[4] = (__bf16)b[0]; r[5] = (__bf16)b[1]; r[6] = (__bf16)b[2]; r[7] = (__bf16)b[3];
  return r;
}

// ---------------- W transpose: W[512 f][512 d] f32 -> Wt[512 d][512 f] bf16 --------
__global__ void transpose_cvt(const float* __restrict__ in, unsigned short* __restrict__ out) {
  __shared__ float tile[32][33];
  const int r0 = blockIdx.x * 32, c0 = blockIdx.y * 32;
  const int tx = threadIdx.x, ty = threadIdx.y;
#pragma unroll
  for (int i = 0; i < 4; ++i) tile[ty + i * 8][tx] = in[(size_t)(r0 + ty + i * 8) * 512 + c0 + tx];
  __syncthreads();
#pragma unroll
  for (int i = 0; i < 4; ++i) {
    const int cc = ty + i * 8;
    out[(size_t)(c0 + cc) * 512 + r0 + tx] = f2bf(tile[tx][cc]);
  }
}

// ---------------- counted-vmcnt ring GEMM (T3+T4+T5) -------------------------------
// 128(M) x 256(N) tile, BK=32, NT K-steps. 512 thr = 8 waves (wr2 x wc4), wave tile
// 64x64. LDS ring[4] x 32KB slot (A fp32 16KB frag-ordered | B bf16 16KB). Stage via
// global_load_lds, 4 insts/wave/tile, 3 tiles ahead. Per iter: stage(t+3) -> phase0
// {4 B + 4 A ds_reads, lgkm(0), setprio, 8 MFMA} -> phase1 {4 A reads, lgkm(0),
// setprio, 8 MFMA} -> vmcnt(8) [retire t+1 ONLY; t+2,t+3 stay in flight] ->
// s_barrier. The memory pipe never drains (T4); latency cover = 2 iters.
template <int APITCH, int BPITCH, int NT, bool IS_Y>
__global__ __launch_bounds__(512, 1) void gemm8p(const float* __restrict__ A0,
                                                 const unsigned short* __restrict__ B0,
                                                 unsigned short* __restrict__ yT,
                                                 int* __restrict__ mask,
                                                 float* __restrict__ out) {
  __shared__ __align__(16) char lds[131072];  // 4 x (A 16KB | B 16KB)

  const int bid = blockIdx.x;
  int b, m0, n0;
  const float* Ab;
  const unsigned short* Bb;
  if constexpr (IS_Y) {
    const int mt = bid >> 1, nt = bid & 1;  // 128 m-tiles (M_flat=16384) x 2 n-tiles
    b = mt >> 4; m0 = (mt & 15) * 128; n0 = nt * 256;
    Ab = A0 + ((size_t)b * 2048 + m0) * APITCH;
    Bb = B0 + (size_t)n0 * BPITCH;
  } else {
    b = bid & 7;  // batch -> XCD pin (yT[b] L2 locality)
    const int idx = bid >> 3;
    m0 = (idx & 15) * 128; n0 = (idx >> 4) * 256;
    Ab = A0 + ((size_t)b * 2048 + m0) * APITCH;
    Bb = B0 + ((size_t)b * 512 + n0) * BPITCH;
  }

  const int tid = threadIdx.x, w = tid >> 6, L = tid & 63;
  const int wr = w >> 2, wc = w & 3, r = L & 15, hi = L >> 4;

  // staging sources (wave w stages A rows w*16..+16, kg j; B rows (w*2+j)*16..+16)
  const char* aSrc = (const char*)(Ab + (size_t)(w * 16 + r) * APITCH + hi * 4);
  const char* bSrc0 = (const char*)(Bb + (size_t)(w * 32 + r) * BPITCH + hi * 8);
  const char* bSrc1 = (const char*)(Bb + (size_t)(w * 32 + 16 + r) * BPITCH + hi * 8);

  // frag read offsets. A frag (rg=wr*4+mi, kg=hi>>1): 1KB; lane chunk c*256 + r*16.
  int aro[4], bro[4];
#pragma unroll
  for (int mi = 0; mi < 4; ++mi)
    aro[mi] = (((wr * 4 + mi) * 2 + (hi >> 1)) << 10) + ((hi & 1) << 9) + r * 16;
#pragma unroll
  for (int ni = 0; ni < 4; ++ni) bro[ni] = 16384 + ((wc * 4 + ni) << 10) + L * 16;

  f32x4 acc[4][4] = {};
  unsigned anz[4] = {0u, 0u, 0u, 0u};

#define STAGE(SLOT, TA)                                                          \
  {                                                                              \
    char* ls = lds + (SLOT) * 32768;                                             \
    gl2lds16(aSrc + (size_t)(TA) * 128, ls + ((w * 2 + 0) << 10));               \
    gl2lds16(aSrc + (size_t)(TA) * 128 + 64, ls + ((w * 2 + 1) << 10));          \
    gl2lds16(bSrc0 + (size_t)(TA) * 64, ls + 16384 + ((w * 2 + 0) << 10));       \
    gl2lds16(bSrc1 + (size_t)(TA) * 64, ls + 16384 + ((w * 2 + 1) << 10));       \
  }

#define ORBITS(mi, lo, hh)                                                       \
  if constexpr (IS_Y) {                                                          \
    if (wc == 0) {                                                               \
      u32x4 u0 = __builtin_bit_cast(u32x4, lo), u1 = __builtin_bit_cast(u32x4, hh); \
      anz[mi] |= (u0[0] | u0[1] | u0[2] | u0[3] | u1[0] | u1[1] | u1[2] | u1[3]) & \
                 0x7fffffffu;                                                    \
    }                                                                            \
  }

  // prologue: tiles 0,1,2 in flight; wait tile0 (vmcnt 8 = leave 2 tiles flying)
  STAGE(0, 0)
  STAGE(1, 1)
  STAGE(2, 2)
  asm volatile("s_waitcnt vmcnt(8)" ::: "memory");
  __builtin_amdgcn_sched_barrier(0);
  __builtin_amdgcn_s_barrier();
  __builtin_amdgcn_sched_barrier(0);

#pragma unroll 1
  for (int t = 0; t < NT; ++t) {
    const int slot = (t + 3) & 3, cur = t & 3;
    const int ta = (t + 3 < NT) ? (t + 3) : (NT - 1);  // clamp: uniform issue count
    STAGE(slot, ta)
    __builtin_amdgcn_sched_barrier(0);
    const char* cb = lds + cur * 32768;

    // phase 0: B all + A mi0,1
    bf16x8 bfr[4];
#pragma unroll
    for (int ni = 0; ni < 4; ++ni) bfr[ni] = *(const bf16x8*)(cb + bro[ni]);
    f32x4 lo0 = *(const f32x4*)(cb + aro[0]), hh0 = *(const f32x4*)(cb + aro[0] + 256);
    f32x4 lo1 = *(const f32x4*)(cb + aro[1]), hh1 = *(const f32x4*)(cb + aro[1] + 256);
    asm volatile("s_waitcnt lgkmcnt(0)" ::: "memory");
    __builtin_amdgcn_sched_barrier(0);
    ORBITS(0, lo0, hh0)
    ORBITS(1, lo1, hh1)
    bf16x8 af0 = cvt8v(lo0, hh0), af1 = cvt8v(lo1, hh1);
    __builtin_amdgcn_s_setprio(1);
#pragma unroll
    for (int ni = 0; ni < 4; ++ni)
      acc[0][ni] = __builtin_amdgcn_mfma_f32_16x16x32_bf16(af0, bfr[ni], acc[0][ni], 0, 0, 0);
#pragma unroll
    for (int ni = 0; ni < 4; ++ni)
      acc[1][ni] = __builtin_amdgcn_mfma_f32_16x16x32_bf16(af1, bfr[ni], acc[1][ni], 0, 0, 0);
    __builtin_amdgcn_s_setprio(0);

    // phase 1: A mi2,3
    f32x4 lo2 = *(const f32x4*)(cb + aro[2]), hh2 = *(const f32x4*)(cb + aro[2] + 256);
    f32x4 lo3 = *(const f32x4*)(cb + aro[3]), hh3 = *(const f32x4*)(cb + aro[3] + 256);
    asm volatile("s_waitcnt lgkmcnt(0)" ::: "memory");
    __builtin_amdgcn_sched_barrier(0);
    ORBITS(2, lo2, hh2)
    ORBITS(3, lo3, hh3)
    bf16x8 af2 = cvt8v(lo2, hh2), af3 = cvt8v(lo3, hh3);
    __builtin_amdgcn_s_setprio(1);
#pragma unroll
    for (int ni = 0; ni < 4; ++ni)
      acc[2][ni] = __builtin_amdgcn_mfma_f32_16x16x32_bf16(af2, bfr[ni], acc[2][ni], 0, 0, 0);
#pragma unroll
    for (int ni = 0; ni < 4; ++ni)
      acc[3][ni] = __builtin_amdgcn_mfma_f32_16x16x32_bf16(af3, bfr[ni], acc[3][ni], 0, 0, 0);
    __builtin_amdgcn_s_setprio(0);

    // retire ONLY tile t+1 (8 = 2 tiles x 4 insts stay in flight) -> barrier
    asm volatile("s_waitcnt vmcnt(8)" ::: "memory");
    __builtin_amdgcn_sched_barrier(0);
    __builtin_amdgcn_s_barrier();
    __builtin_amdgcn_sched_barrier(0);
  }
  asm volatile("s_waitcnt vmcnt(0)" ::: "memory");

#undef STAGE
#undef ORBITS

  if constexpr (IS_Y) {
    if (wc == 0) {
#pragma unroll
      for (int mi = 0; mi < 4; ++mi) {
        unsigned v = anz[mi];
        v |= __shfl_xor(v, 16);
        v |= __shfl_xor(v, 32);
        if (hi == 0) mask[b * 2048 + m0 + wr * 64 + mi * 16 + r] = (v != 0u) ? 1 : 0;
      }
    }
    // yT[b][d][n] store: rr runs along n -> contiguous 8B stores
#pragma unroll
    for (int mi = 0; mi < 4; ++mi)
#pragma unroll
      for (int ni = 0; ni < 4; ++ni) {
        const int col = n0 + wc * 64 + ni * 16 + r;
        const int nrow = m0 + wr * 64 + mi * 16 + hi * 4;
        ushort4 s;
        s.x = f2bf(acc[mi][ni][0]);
        s.y = f2bf(acc[mi][ni][1]);
        s.z = f2bf(acc[mi][ni][2]);
        s.w = f2bf(acc[mi][ni][3]);
        *(ushort4*)(yT + (((size_t)b * 512 + col) << 11) + nrow) = s;
      }
  } else {
    const int* mrow = mask + b * 2048 + m0 + wr * 64;
#pragma unroll
    for (int mi = 0; mi < 4; ++mi) {
      const int4 mv = *(const int4*)(mrow + mi * 16 + hi * 4);
      const int mvv[4] = {mv.x, mv.y, mv.z, mv.w};
#pragma unroll
      for (int ni = 0; ni < 4; ++ni) {
        const int col = n0 + wc * 64 + ni * 16 + r;
        float* op = out + (size_t)(b * 2048 + m0 + wr * 64 + mi * 16 + hi * 4) * 512 + col;
#pragma unroll
        for (int rr = 0; rr < 4; ++rr) {
          float v = fmaxf(acc[mi][ni][rr], 0.0f);
          if (mvv[rr] == 0) v = 0.0f;
          op[(size_t)rr * 512] = v;
        }
      }
    }
  }
}

// ---------------- launch ----------------------------------------------------------
extern "C" void kernel_launch(void* const* d_in, const int* in_sizes, int n_in,
                              void* d_out, int out_size, void* d_ws, size_t ws_size,
                              hipStream_t stream) {
  const float* x = (const float*)d_in[0];   // [8][2048][512]
  const float* a = (const float*)d_in[1];   // [8][2048][2048]
  const float* wk = (const float*)d_in[2];  // [512][512]
  float* out = (float*)d_out;               // [8][2048][512]

  char* ws = (char*)d_ws;
  unsigned short* wT = (unsigned short*)ws;                 // 512 KB
  unsigned short* yT = (unsigned short*)(ws + (1u << 19));  // 16 MB
  int* mask = (int*)(ws + (1u << 19) + (16u << 20));        // 64 KB

  transpose_cvt<<<dim3(16, 16), dim3(32, 8), 0, stream>>>(wk, wT);
  // y^T = (x @ W)^T (bf16) + exact row mask.  M_flat=16384, N=512, K=512.
  gemm8p<512, 512, 16, true><<<256, 512, 0, stream>>>(x, wT, yT, mask, nullptr);
  // out = relu(a @ y) * mask.  Per batch M=2048, N=512 (d), K=2048 (n).
  gemm8p<2048, 2048, 64, false><<<256, 512, 0, stream>>>(a, yT, nullptr, mask, out);
}